// Round 1
// baseline (13945.711 us; speedup 1.0000x reference)
//
#include <hip/hip_runtime.h>

// Problem constants
constexpr int BATCH = 8;
constexpr int CH    = 256;   // C_VIS == C_GRAPH == C_OUT == 256
constexpr int H     = 96;
constexpr int W     = 96;
constexpr int HW    = H * W;                    // 9216
constexpr long PLANE_ELEMS = (long)BATCH * CH * HW;  // 18,874,368

// ---------------------------------------------------------------------------
// Conv 3x3 SAME, fp32 direct convolution.
// Block: 256 threads -> tx in [0,8) (4 px each => 32 px), ty in [0,16), tc in [0,2)
// Each thread computes 4 consecutive x-pixels for 2 consecutive co.
// Block output tile: 32(x) x 16(y) x 4(co).
// Grid: (W/32=3, H/16=6, B*(C/4)=512)
// ---------------------------------------------------------------------------
#define SIN_STRIDE 35   // 34 + 1 pad: breaks stride-34's 8-way bank conflict

__global__ __launch_bounds__(256) void conv3x3_kernel(
    const float* __restrict__ in,    // [B, C, H, W]
    const float* __restrict__ wt,    // [Co, Ci, 3, 3]
    const float* __restrict__ bias,  // [Co]
    float* __restrict__ out)         // [B, Co, H, W]
{
  const int tid = threadIdx.x;
  const int tx  = tid & 7;
  const int ty  = (tid >> 3) & 15;
  const int tc  = tid >> 7;

  const int bz  = blockIdx.z;
  const int b   = bz >> 6;
  const int cog = bz & 63;
  const int co0 = cog * 4;
  const int x0  = blockIdx.x * 32;
  const int y0  = blockIdx.y * 16;

  __shared__ float sW[4 * 2304];           // 4 co x (256 ci * 9 taps), 36 KB
  __shared__ float sIn[18 * SIN_STRIDE];   // 18 rows x 34 cols (+pad), ~2.5 KB

  // Preload all weights for this block's 4 output channels (coalesced).
  for (int idx = tid; idx < 4 * 2304; idx += 256) {
    int cl = idx / 2304;
    int r  = idx - cl * 2304;
    sW[idx] = wt[(long)(co0 + cl) * 2304 + r];
  }

  float acc[2][4];
#pragma unroll
  for (int u = 0; u < 2; ++u) {
    float bv = bias[co0 + tc * 2 + u];
#pragma unroll
    for (int p = 0; p < 4; ++p) acc[u][p] = bv;
  }

  const float* inb = in + (long)b * CH * HW;

  for (int ci = 0; ci < CH; ++ci) {
    __syncthreads();   // protects sIn reuse (and first-iter sW visibility)
    // Stage 18x34 input tile (halo = 1) with zero padding at borders.
    for (int idx = tid; idx < 18 * 34; idx += 256) {
      int r  = idx / 34;
      int cc = idx - r * 34;
      int gy = y0 - 1 + r;
      int gx = x0 - 1 + cc;
      float v = 0.f;
      if (gy >= 0 && gy < H && gx >= 0 && gx < W)
        v = inb[(long)ci * HW + gy * W + gx];
      sIn[r * SIN_STRIDE + cc] = v;
    }
    __syncthreads();

#pragma unroll
    for (int dy = 0; dy < 3; ++dy) {
      float rr[6];
#pragma unroll
      for (int j = 0; j < 6; ++j)
        rr[j] = sIn[(ty + dy) * SIN_STRIDE + tx * 4 + j];
#pragma unroll
      for (int u = 0; u < 2; ++u) {
        const float* wrow = &sW[(tc * 2 + u) * 2304 + ci * 9 + dy * 3];
#pragma unroll
        for (int dx = 0; dx < 3; ++dx) {
          float wv = wrow[dx];
#pragma unroll
          for (int p = 0; p < 4; ++p)
            acc[u][p] = fmaf(wv, rr[p + dx], acc[u][p]);
        }
      }
    }
  }

  const int y = y0 + ty;
  const int x = x0 + tx * 4;
#pragma unroll
  for (int u = 0; u < 2; ++u) {
    int co = co0 + tc * 2 + u;
    float4 v4 = make_float4(acc[u][0], acc[u][1], acc[u][2], acc[u][3]);
    *reinterpret_cast<float4*>(&out[(((long)b * CH + co) * H + y) * W + x]) = v4;
  }
}

// ---------------------------------------------------------------------------
// Row attention per (b,c) plane: attn = softmax(Q K^T / sqrt(W)) ; out = attn V
// One block (256 threads = 4 waves) per plane. Each wave owns 24 rows; within
// a row, lanes parallelize over the 96 columns (col = lane, and 64+lane for
// lane < 32).
// ---------------------------------------------------------------------------
__global__ __launch_bounds__(256) void attn_kernel(
    const float* __restrict__ q,
    const float* __restrict__ k,
    const float* __restrict__ v,
    float* __restrict__ outf)
{
  __shared__ float sQ[96 * 96];          // [i][w] — broadcast reads only
  __shared__ float sKt[96 * 128];        // [w][j], j zero-padded to 128
  __shared__ float sV[96 * 96 + 64];     // [j][w], +64 pad: OOB-safe masked lanes
  __shared__ float sP[4 * 96];           // per-wave softmax row

  const int tid  = threadIdx.x;
  const int lane = tid & 63;
  const int wv   = tid >> 6;
  const long plane = (long)blockIdx.x * HW;

  for (int idx = tid; idx < HW; idx += 256) {
    sQ[idx] = q[plane + idx];
    sV[idx] = v[plane + idx];
  }
  for (int idx = tid; idx < HW; idx += 256) {
    int j = idx / 96, w = idx - j * 96;
    sKt[w * 128 + j] = k[plane + idx];   // transpose on store (one-time cost)
  }
  for (int idx = tid; idx < 96 * 32; idx += 256) {
    int w = idx >> 5, j = 96 + (idx & 31);
    sKt[w * 128 + j] = 0.f;              // pad columns -> harmless for lanes>=32
  }
  __syncthreads();

  const float scale = 0.10206207261596575f;  // 1/sqrt(96)

  for (int i = wv; i < 96; i += 4) {
    // --- scores s[j] = sum_w q[i,w] * k[j,w] ---
    float s0 = 0.f, s1 = 0.f;
#pragma unroll 8
    for (int w = 0; w < 96; ++w) {
      float qv = sQ[i * 96 + w];                     // LDS broadcast
      s0 = fmaf(qv, sKt[w * 128 + lane], s0);        // j = lane
      s1 = fmaf(qv, sKt[w * 128 + 64 + lane], s1);   // j = 64+lane (pad-safe)
    }
    s0 *= scale;
    s1 = (lane < 32) ? s1 * scale : -3.0e38f;

    // --- softmax over 96 columns ---
    float m = fmaxf(s0, s1);
#pragma unroll
    for (int off = 32; off; off >>= 1) m = fmaxf(m, __shfl_xor(m, off));
    float p0 = __expf(s0 - m);
    float p1 = (lane < 32) ? __expf(s1 - m) : 0.f;
    float sum = p0 + p1;
#pragma unroll
    for (int off = 32; off; off >>= 1) sum += __shfl_xor(sum, off);
    float inv = 1.f / sum;
    p0 *= inv;
    p1 *= inv;

    sP[wv * 96 + lane] = p0;
    if (lane < 32) sP[wv * 96 + 64 + lane] = p1;
    // In-wave LDS ordering: compiler inserts lgkmcnt waits before the reads.

    // --- fused[i,w] = sum_j p[j] * v[j,w] ---
    float f0 = 0.f, f1 = 0.f;
#pragma unroll 8
    for (int j = 0; j < 96; ++j) {
      float pj = sP[wv * 96 + j];                    // LDS broadcast
      f0 = fmaf(pj, sV[j * 96 + lane], f0);          // w = lane
      f1 = fmaf(pj, sV[j * 96 + 64 + lane], f1);     // w = 64+lane (pad-safe)
    }
    outf[plane + i * 96 + lane] = f0;
    if (lane < 32) outf[plane + i * 96 + 64 + lane] = f1;
  }
}

// ---------------------------------------------------------------------------
extern "C" void kernel_launch(void* const* d_in, const int* in_sizes, int n_in,
                              void* d_out, int out_size, void* d_ws, size_t ws_size,
                              hipStream_t stream) {
  (void)in_sizes; (void)n_in; (void)out_size; (void)ws_size;

  const float* feats = (const float*)d_in[0];
  const float* graph = (const float*)d_in[1];
  const float* wq    = (const float*)d_in[2];
  const float* bq    = (const float*)d_in[3];
  const float* wk    = (const float*)d_in[4];
  const float* bk    = (const float*)d_in[5];
  const float* wv    = (const float*)d_in[6];
  const float* bv    = (const float*)d_in[7];
  const float* wo    = (const float*)d_in[8];
  const float* bo    = (const float*)d_in[9];
  float* out = (float*)d_out;

  float* qb = (float*)d_ws;            // also receives fused output
  float* kb = qb + PLANE_ELEMS;
  float* vb = kb + PLANE_ELEMS;

  dim3 cgrid(3, 6, BATCH * (CH / 4));

  conv3x3_kernel<<<cgrid, 256, 0, stream>>>(graph, wq, bq, qb);
  conv3x3_kernel<<<cgrid, 256, 0, stream>>>(feats, wk, bk, kb);
  conv3x3_kernel<<<cgrid, 256, 0, stream>>>(feats, wv, bv, vb);

  attn_kernel<<<dim3(BATCH * CH), 256, 0, stream>>>(qb, kb, vb, qb);

  conv3x3_kernel<<<cgrid, 256, 0, stream>>>(qb, wo, bo, out);
}

// Round 2
// 1363.199 us; speedup vs baseline: 10.2301x; 10.2301x over previous
//
#include <hip/hip_runtime.h>
#include <hip/hip_bf16.h>

// Problem constants
constexpr int BATCH = 8;
constexpr int CH    = 256;
constexpr int H     = 96;
constexpr int W     = 96;
constexpr int HW    = H * W;                         // 9216
constexpr long PLANE_ELEMS = (long)BATCH * CH * HW;  // 18,874,368

typedef short  bf16x8_t __attribute__((ext_vector_type(8)));
typedef float  f32x4_t  __attribute__((ext_vector_type(4)));

// ---------------------------------------------------------------------------
// NCHW fp32 -> NHWC bf16 (tiled transpose). grid (HW/32, C/32, B), 256 thr.
// ---------------------------------------------------------------------------
__global__ __launch_bounds__(256) void nchw_f32_to_nhwc_bf16(
    const float* __restrict__ in, __hip_bfloat16* __restrict__ out)
{
  __shared__ float t[32][33];
  const int tid = threadIdx.x;
  const int p0 = blockIdx.x * 32;
  const int c0 = blockIdx.y * 32;
  const int b  = blockIdx.z;
  const int tp = tid & 31, tc8 = tid >> 5;
#pragma unroll
  for (int i = 0; i < 4; ++i) {
    int c = tc8 + i * 8;
    t[c][tp] = in[((long)(b * 256 + c0 + c)) * HW + p0 + tp];
  }
  __syncthreads();
  const int wc = tid & 31, wp8 = tid >> 5;
#pragma unroll
  for (int i = 0; i < 4; ++i) {
    int p = wp8 + i * 8;
    out[((long)b * HW + p0 + p) * 256 + c0 + wc] = __float2bfloat16(t[wc][p]);
  }
}

// ---------------------------------------------------------------------------
// Weights [Co,Ci,3,3] fp32 -> [tap][Co][Ci] bf16.  grid 2304 x 256.
// ---------------------------------------------------------------------------
__global__ __launch_bounds__(256) void w_oihw_to_tap_bf16(
    const float* __restrict__ w, __hip_bfloat16* __restrict__ wt)
{
  int idx = blockIdx.x * 256 + threadIdx.x;   // (tap*256+co)*256+ci, total 589824
  int ci  = idx & 255;
  int co  = (idx >> 8) & 255;
  int tap = idx >> 16;
  wt[idx] = __float2bfloat16(w[(co * 256 + ci) * 9 + tap]);
}

// ---------------------------------------------------------------------------
// Conv 3x3 SAME via bf16 MFMA implicit GEMM (tap-decomposed).
// Block: 256 thr = 4 waves. Block tile: 128 co x (2 rows x 96 px = 192 px).
// Wave tile: 64 co (m=0..3) x 96 px (n=0..5), mfma_f32_16x16x32_bf16.
// K loop: 8 ci-chunks of 32, x 9 taps (one K=32 MFMA step per tap).
// Input staged in LDS [4 rows][98 x][ci pad 40] (80B pitch -> 2-way banks only),
// double-buffered with reg-staged prefetch. Weights (L2-resident) loaded as
// A-fragments straight from global, prefetched one tap ahead.
// grid (2, 48, 8)
// ---------------------------------------------------------------------------
__global__ __launch_bounds__(256, 2) void conv3x3_mfma(
    const ushort* __restrict__ in_nhwc,   // [B][96][96][256] bf16 bits
    const ushort* __restrict__ wt,        // [9][256][256] bf16 bits
    const float* __restrict__ bias,       // [256]
    float* __restrict__ out)              // [B][256][96][96] f32
{
  const int tid  = threadIdx.x;
  const int lane = tid & 63;
  const int wv   = tid >> 6;
  const int wm   = wv & 1;        // co half (0/1 -> 64 co each)
  const int wn   = wv >> 1;       // pixel half (row within tile)
  const int l15  = lane & 15;
  const int lg   = lane >> 4;

  const int co0 = blockIdx.x * 128;
  const int y0  = blockIdx.y * 2;
  const int b   = blockIdx.z;

  __shared__ ushort sIn[2][4 * 98 * 40];   // 2 x 31,360 B = 62,720 B

  f32x4_t acc[4][6];
#pragma unroll
  for (int m = 0; m < 4; ++m)
#pragma unroll
    for (int n = 0; n < 6; ++n)
      acc[m][n] = (f32x4_t){0.f, 0.f, 0.f, 0.f};

  // --- staging helpers: 1568 16B units = 4 rr x 98 xx x 4 ci-groups ---
  auto stage_load = [&](int chunk, int4* regs) {
    const int ci0 = chunk * 32;
#pragma unroll
    for (int it = 0; it < 7; ++it) {
      int u = tid + it * 256;
      int4 v = make_int4(0, 0, 0, 0);
      if (u < 1568) {
        int g  = u & 3;
        int q  = u >> 2;          // [0,392)
        int xx = q % 98;
        int rr = q / 98;
        int y = y0 - 1 + rr, x = xx - 1;
        if (y >= 0 && y < H && x >= 0 && x < W) {
          v = *(const int4*)&in_nhwc[((b * 96 + y) * 96 + x) * 256 + ci0 + g * 8];
        }
      }
      regs[it] = v;
    }
  };
  auto stage_write = [&](int bi, const int4* regs) {
#pragma unroll
    for (int it = 0; it < 7; ++it) {
      int u = tid + it * 256;
      if (u < 1568) {
        int g  = u & 3;
        int q  = u >> 2;
        int xx = q % 98;
        int rr = q / 98;
        *(int4*)((char*)&sIn[bi][0] + (rr * 98 + xx) * 80 + g * 16) = regs[it];
      }
    }
  };
  auto lds_b = [&](int bi, int rr, int xx) -> bf16x8_t {
    return *(const bf16x8_t*)((const char*)&sIn[bi][0] + (rr * 98 + xx) * 80 + lg * 16);
  };
  auto gld_a = [&](int tap, int m, int ci0) -> bf16x8_t {
    int co = co0 + wm * 64 + m * 16 + l15;
    return *(const bf16x8_t*)&wt[((tap * 256 + co) << 8) + ci0 + lg * 8];
  };

  int4 pre[7];
  stage_load(0, pre);
  stage_write(0, pre);
  __syncthreads();

  for (int c = 0; c < 8; ++c) {
    const int bi  = c & 1;
    const int ci0 = c * 32;
    if (c < 7) stage_load(c + 1, pre);    // issue next chunk's global loads early

    bf16x8_t a_cur[4], a_nxt[4], b_cur[6], b_nxt[6];
#pragma unroll
    for (int m = 0; m < 4; ++m) a_cur[m] = gld_a(0, m, ci0);
#pragma unroll
    for (int n = 0; n < 6; ++n) b_cur[n] = lds_b(bi, wn + 0, n * 16 + l15 + 0);

#pragma unroll
    for (int tap = 0; tap < 9; ++tap) {
      if (tap < 8) {
        const int dyn = (tap + 1) / 3, dxn = (tap + 1) % 3;
#pragma unroll
        for (int m = 0; m < 4; ++m) a_nxt[m] = gld_a(tap + 1, m, ci0);
#pragma unroll
        for (int n = 0; n < 6; ++n) b_nxt[n] = lds_b(bi, wn + dyn, n * 16 + l15 + dxn);
      }
#pragma unroll
      for (int m = 0; m < 4; ++m)
#pragma unroll
        for (int n = 0; n < 6; ++n)
          acc[m][n] = __builtin_amdgcn_mfma_f32_16x16x32_bf16(
              a_cur[m], b_cur[n], acc[m][n], 0, 0, 0);
#pragma unroll
      for (int m = 0; m < 4; ++m) a_cur[m] = a_nxt[m];
#pragma unroll
      for (int n = 0; n < 6; ++n) b_cur[n] = b_nxt[n];
    }

    if (c < 7) stage_write((c + 1) & 1, pre);
    __syncthreads();
  }

  // --- epilogue: bias + fp32 NCHW store ---
  // C/D layout (m89): col = lane&15 -> pixel, row = (lane>>4)*4 + r -> co
  const int y = y0 + wn;
#pragma unroll
  for (int m = 0; m < 4; ++m) {
    const int cobase = co0 + wm * 64 + m * 16 + lg * 4;
#pragma unroll
    for (int r = 0; r < 4; ++r) {
      const int co = cobase + r;
      const float bv = bias[co];
#pragma unroll
      for (int n = 0; n < 6; ++n) {
        out[((long)(b * 256 + co) * 96 + y) * 96 + n * 16 + l15] = acc[m][n][r] + bv;
      }
    }
  }
}

// ---------------------------------------------------------------------------
// Row attention per (b,c) plane (unchanged from round 1, fp32).
// ---------------------------------------------------------------------------
__global__ __launch_bounds__(256) void attn_kernel(
    const float* __restrict__ q,
    const float* __restrict__ k,
    const float* __restrict__ v,
    float* __restrict__ outf)
{
  __shared__ float sQ[96 * 96];
  __shared__ float sKt[96 * 128];
  __shared__ float sV[96 * 96 + 64];
  __shared__ float sP[4 * 96];

  const int tid  = threadIdx.x;
  const int lane = tid & 63;
  const int wv   = tid >> 6;
  const long plane = (long)blockIdx.x * HW;

  for (int idx = tid; idx < HW; idx += 256) {
    sQ[idx] = q[plane + idx];
    sV[idx] = v[plane + idx];
  }
  for (int idx = tid; idx < HW; idx += 256) {
    int j = idx / 96, w = idx - j * 96;
    sKt[w * 128 + j] = k[plane + idx];
  }
  for (int idx = tid; idx < 96 * 32; idx += 256) {
    int w = idx >> 5, j = 96 + (idx & 31);
    sKt[w * 128 + j] = 0.f;
  }
  __syncthreads();

  const float scale = 0.10206207261596575f;  // 1/sqrt(96)

  for (int i = wv; i < 96; i += 4) {
    float s0 = 0.f, s1 = 0.f;
#pragma unroll 8
    for (int w = 0; w < 96; ++w) {
      float qv = sQ[i * 96 + w];
      s0 = fmaf(qv, sKt[w * 128 + lane], s0);
      s1 = fmaf(qv, sKt[w * 128 + 64 + lane], s1);
    }
    s0 *= scale;
    s1 = (lane < 32) ? s1 * scale : -3.0e38f;

    float m = fmaxf(s0, s1);
#pragma unroll
    for (int off = 32; off; off >>= 1) m = fmaxf(m, __shfl_xor(m, off));
    float p0 = __expf(s0 - m);
    float p1 = (lane < 32) ? __expf(s1 - m) : 0.f;
    float sum = p0 + p1;
#pragma unroll
    for (int off = 32; off; off >>= 1) sum += __shfl_xor(sum, off);
    float inv = 1.f / sum;
    p0 *= inv;
    p1 *= inv;

    sP[wv * 96 + lane] = p0;
    if (lane < 32) sP[wv * 96 + 64 + lane] = p1;

    float f0 = 0.f, f1 = 0.f;
#pragma unroll 8
    for (int j = 0; j < 96; ++j) {
      float pj = sP[wv * 96 + j];
      f0 = fmaf(pj, sV[j * 96 + lane], f0);
      f1 = fmaf(pj, sV[j * 96 + 64 + lane], f1);
    }
    outf[plane + i * 96 + lane] = f0;
    if (lane < 32) outf[plane + i * 96 + 64 + lane] = f1;
  }
}

// ---------------------------------------------------------------------------
extern "C" void kernel_launch(void* const* d_in, const int* in_sizes, int n_in,
                              void* d_out, int out_size, void* d_ws, size_t ws_size,
                              hipStream_t stream) {
  (void)in_sizes; (void)n_in; (void)out_size; (void)ws_size;

  const float* feats = (const float*)d_in[0];
  const float* graph = (const float*)d_in[1];
  const float* wq    = (const float*)d_in[2];
  const float* bq    = (const float*)d_in[3];
  const float* wk    = (const float*)d_in[4];
  const float* bk    = (const float*)d_in[5];
  const float* wv    = (const float*)d_in[6];
  const float* bv    = (const float*)d_in[7];
  const float* wo    = (const float*)d_in[8];
  const float* bo    = (const float*)d_in[9];
  float* out = (float*)d_out;

  char* ws = (char*)d_ws;
  const long planeBytesF32 = PLANE_ELEMS * 4;           // 75,497,472
  float* qb = (float*)ws;                               // also receives fused
  float* kb = (float*)(ws + planeBytesF32);
  float* vb = (float*)(ws + 2 * planeBytesF32);
  __hip_bfloat16* nhwc = (__hip_bfloat16*)(ws + 3 * planeBytesF32);   // 37.7 MB
  __hip_bfloat16* wtq  = (__hip_bfloat16*)(ws + 3 * planeBytesF32 + PLANE_ELEMS * 2);
  __hip_bfloat16* wtk  = wtq + 9 * 256 * 256;
  __hip_bfloat16* wtv  = wtk + 9 * 256 * 256;
  __hip_bfloat16* wto  = wtv + 9 * 256 * 256;

  dim3 tgrid(HW / 32, CH / 32, BATCH);   // (288, 8, 8)
  dim3 wgrid(2304);
  dim3 cgrid(2, 48, BATCH);
  dim3 agrid(BATCH * CH);

  w_oihw_to_tap_bf16<<<wgrid, 256, 0, stream>>>(wq, wtq);
  w_oihw_to_tap_bf16<<<wgrid, 256, 0, stream>>>(wk, wtk);
  w_oihw_to_tap_bf16<<<wgrid, 256, 0, stream>>>(wv, wtv);
  w_oihw_to_tap_bf16<<<wgrid, 256, 0, stream>>>(wo, wto);

  nchw_f32_to_nhwc_bf16<<<tgrid, 256, 0, stream>>>(feats, nhwc);
  conv3x3_mfma<<<cgrid, 256, 0, stream>>>((const ushort*)nhwc, (const ushort*)wtk, bk, kb);
  conv3x3_mfma<<<cgrid, 256, 0, stream>>>((const ushort*)nhwc, (const ushort*)wtv, bv, vb);

  nchw_f32_to_nhwc_bf16<<<tgrid, 256, 0, stream>>>(graph, nhwc);
  conv3x3_mfma<<<cgrid, 256, 0, stream>>>((const ushort*)nhwc, (const ushort*)wtq, bq, qb);

  attn_kernel<<<agrid, 256, 0, stream>>>(qb, kb, vb, qb);

  nchw_f32_to_nhwc_bf16<<<tgrid, 256, 0, stream>>>(qb, nhwc);
  conv3x3_mfma<<<cgrid, 256, 0, stream>>>((const ushort*)nhwc, (const ushort*)wto, bo, out);
}

// Round 3
// 707.282 us; speedup vs baseline: 19.7173x; 1.9274x over previous
//
#include <hip/hip_runtime.h>
#include <hip/hip_bf16.h>

// Problem constants
constexpr int BATCH = 8;
constexpr int CH    = 256;
constexpr int H     = 96;
constexpr int W     = 96;
constexpr int HW    = H * W;                         // 9216
constexpr long PLANE_ELEMS = (long)BATCH * CH * HW;  // 18,874,368

typedef short  bf16x8_t __attribute__((ext_vector_type(8)));
typedef float  f32x4_t  __attribute__((ext_vector_type(4)));

__device__ inline uint pk2_bf16(float a, float b) {
  ushort lo = __bfloat16_as_ushort(__float2bfloat16(a));
  ushort hi = __bfloat16_as_ushort(__float2bfloat16(b));
  return (uint)lo | ((uint)hi << 16);
}

// ---------------------------------------------------------------------------
// NCHW fp32 -> NHWC bf16 (tiled transpose). grid (HW/32, C/32, B), 256 thr.
// ---------------------------------------------------------------------------
__global__ __launch_bounds__(256) void nchw_f32_to_nhwc_bf16(
    const float* __restrict__ in, ushort* __restrict__ out)
{
  __shared__ float t[32][33];
  const int tid = threadIdx.x;
  const int p0 = blockIdx.x * 32;
  const int c0 = blockIdx.y * 32;
  const int b  = blockIdx.z;
  const int tp = tid & 31, tc8 = tid >> 5;
#pragma unroll
  for (int i = 0; i < 4; ++i) {
    int c = tc8 + i * 8;
    t[c][tp] = in[((long)(b * 256 + c0 + c)) * HW + p0 + tp];
  }
  __syncthreads();
  const int wc = tid & 31, wp8 = tid >> 5;
#pragma unroll
  for (int i = 0; i < 4; ++i) {
    int p = wp8 + i * 8;
    out[((long)b * HW + p0 + p) * 256 + c0 + wc] =
        __bfloat16_as_ushort(__float2bfloat16(t[wc][p]));
  }
}

// ---------------------------------------------------------------------------
// NCHW bf16 -> NHWC bf16 (for the fused attention output feeding conv O).
// ---------------------------------------------------------------------------
__global__ __launch_bounds__(256) void nchw_bf16_to_nhwc_bf16(
    const ushort* __restrict__ in, ushort* __restrict__ out)
{
  __shared__ ushort t[32][34];
  const int tid = threadIdx.x;
  const int p0 = blockIdx.x * 32;
  const int c0 = blockIdx.y * 32;
  const int b  = blockIdx.z;
  const int tp = tid & 31, tc8 = tid >> 5;
#pragma unroll
  for (int i = 0; i < 4; ++i) {
    int c = tc8 + i * 8;
    t[c][tp] = in[((long)(b * 256 + c0 + c)) * HW + p0 + tp];
  }
  __syncthreads();
  const int wc = tid & 31, wp8 = tid >> 5;
#pragma unroll
  for (int i = 0; i < 4; ++i) {
    int p = wp8 + i * 8;
    out[((long)b * HW + p0 + p) * 256 + c0 + wc] = t[wc][p];
  }
}

// ---------------------------------------------------------------------------
// Weights [Co,Ci,3,3] fp32 -> [tap][Co][Ci] bf16.  grid 2304 x 256.
// ---------------------------------------------------------------------------
__global__ __launch_bounds__(256) void w_oihw_to_tap_bf16(
    const float* __restrict__ w, ushort* __restrict__ wt)
{
  int idx = blockIdx.x * 256 + threadIdx.x;
  int ci  = idx & 255;
  int co  = (idx >> 8) & 255;
  int tap = idx >> 16;
  wt[idx] = __bfloat16_as_ushort(__float2bfloat16(w[(co * 256 + ci) * 9 + tap]));
}

// ---------------------------------------------------------------------------
// Conv 3x3 SAME via bf16 MFMA implicit GEMM (tap-decomposed), templated output.
// Block tile 128 co x 192 px, wave 64co x 96px, mfma_f32_16x16x32_bf16.
// grid (2, 48, 8)
// ---------------------------------------------------------------------------
__device__ inline void store_conv(float* out, long idx, float v) { out[idx] = v; }
__device__ inline void store_conv(ushort* out, long idx, float v) {
  out[idx] = __bfloat16_as_ushort(__float2bfloat16(v));
}

template <typename OutT>
__global__ __launch_bounds__(256, 2) void conv3x3_mfma(
    const ushort* __restrict__ in_nhwc,   // [B][96][96][256] bf16 bits
    const ushort* __restrict__ wt,        // [9][256][256] bf16 bits
    const float* __restrict__ bias,       // [256]
    OutT* __restrict__ out)               // [B][256][96][96]
{
  const int tid  = threadIdx.x;
  const int lane = tid & 63;
  const int wv   = tid >> 6;
  const int wm   = wv & 1;
  const int wn   = wv >> 1;
  const int l15  = lane & 15;
  const int lg   = lane >> 4;

  const int co0 = blockIdx.x * 128;
  const int y0  = blockIdx.y * 2;
  const int b   = blockIdx.z;

  __shared__ ushort sIn[2][4 * 98 * 40];

  f32x4_t acc[4][6];
#pragma unroll
  for (int m = 0; m < 4; ++m)
#pragma unroll
    for (int n = 0; n < 6; ++n)
      acc[m][n] = (f32x4_t){0.f, 0.f, 0.f, 0.f};

  auto stage_load = [&](int chunk, int4* regs) {
    const int ci0 = chunk * 32;
#pragma unroll
    for (int it = 0; it < 7; ++it) {
      int u = tid + it * 256;
      int4 v = make_int4(0, 0, 0, 0);
      if (u < 1568) {
        int g  = u & 3;
        int q  = u >> 2;
        int xx = q % 98;
        int rr = q / 98;
        int y = y0 - 1 + rr, x = xx - 1;
        if (y >= 0 && y < H && x >= 0 && x < W) {
          v = *(const int4*)&in_nhwc[((b * 96 + y) * 96 + x) * 256 + ci0 + g * 8];
        }
      }
      regs[it] = v;
    }
  };
  auto stage_write = [&](int bi, const int4* regs) {
#pragma unroll
    for (int it = 0; it < 7; ++it) {
      int u = tid + it * 256;
      if (u < 1568) {
        int g  = u & 3;
        int q  = u >> 2;
        int xx = q % 98;
        int rr = q / 98;
        *(int4*)((char*)&sIn[bi][0] + (rr * 98 + xx) * 80 + g * 16) = regs[it];
      }
    }
  };
  auto lds_b = [&](int bi, int rr, int xx) -> bf16x8_t {
    return *(const bf16x8_t*)((const char*)&sIn[bi][0] + (rr * 98 + xx) * 80 + lg * 16);
  };
  auto gld_a = [&](int tap, int m, int ci0) -> bf16x8_t {
    int co = co0 + wm * 64 + m * 16 + l15;
    return *(const bf16x8_t*)&wt[((tap * 256 + co) << 8) + ci0 + lg * 8];
  };

  int4 pre[7];
  stage_load(0, pre);
  stage_write(0, pre);
  __syncthreads();

  for (int c = 0; c < 8; ++c) {
    const int bi  = c & 1;
    const int ci0 = c * 32;
    if (c < 7) stage_load(c + 1, pre);

    bf16x8_t a_cur[4], a_nxt[4], b_cur[6], b_nxt[6];
#pragma unroll
    for (int m = 0; m < 4; ++m) a_cur[m] = gld_a(0, m, ci0);
#pragma unroll
    for (int n = 0; n < 6; ++n) b_cur[n] = lds_b(bi, wn + 0, n * 16 + l15 + 0);

#pragma unroll
    for (int tap = 0; tap < 9; ++tap) {
      if (tap < 8) {
        const int dyn = (tap + 1) / 3, dxn = (tap + 1) % 3;
#pragma unroll
        for (int m = 0; m < 4; ++m) a_nxt[m] = gld_a(tap + 1, m, ci0);
#pragma unroll
        for (int n = 0; n < 6; ++n) b_nxt[n] = lds_b(bi, wn + dyn, n * 16 + l15 + dxn);
      }
#pragma unroll
      for (int m = 0; m < 4; ++m)
#pragma unroll
        for (int n = 0; n < 6; ++n)
          acc[m][n] = __builtin_amdgcn_mfma_f32_16x16x32_bf16(
              a_cur[m], b_cur[n], acc[m][n], 0, 0, 0);
#pragma unroll
      for (int m = 0; m < 4; ++m) a_cur[m] = a_nxt[m];
#pragma unroll
      for (int n = 0; n < 6; ++n) b_cur[n] = b_nxt[n];
    }

    if (c < 7) stage_write((c + 1) & 1, pre);
    __syncthreads();
  }

  const int y = y0 + wn;
#pragma unroll
  for (int m = 0; m < 4; ++m) {
    const int cobase = co0 + wm * 64 + m * 16 + lg * 4;
#pragma unroll
    for (int r = 0; r < 4; ++r) {
      const int co = cobase + r;
      const float bv = bias[co];
#pragma unroll
      for (int n = 0; n < 6; ++n) {
        store_conv(out, ((long)(b * 256 + co) * 96 + y) * 96 + n * 16 + l15,
                   acc[m][n][r] + bv);
      }
    }
  }
}

// ---------------------------------------------------------------------------
// MFMA row attention. One block (384 thr = 6 waves) per (b,c) plane.
// Wave wv owns query rows i0 = wv*16 .. +15.
// Swapped QK^T: mfma(A=K_frag, B=Q_frag) -> lane(l15=i) holds 24 j-scores
// (j = jt*16 + lg*4 + r). Softmax = in-register + shfl_xor(16,32).
// P packed bf16 into per-wave LDS; PV: mfma(A=P_frag, B=Vt_frag).
// ---------------------------------------------------------------------------
constexpr int APITCH = 104;   // LDS row pitch in bf16 elems (208 B, 16B-aligned)

__global__ __launch_bounds__(384, 3) void attn_mfma(
    const ushort* __restrict__ q,
    const ushort* __restrict__ k,
    const ushort* __restrict__ v,
    ushort* __restrict__ outf)
{
  __shared__ ushort sK [96 * APITCH];       // [j][w]
  __shared__ ushort sVt[96 * APITCH];       // [w][j]  (V transposed)
  __shared__ ushort sP [6 * 16 * APITCH];   // per-wave [i_local][j]

  const int tid  = threadIdx.x;
  const int lane = tid & 63;
  const int wv   = tid >> 6;      // 0..5
  const int l15  = lane & 15;
  const int lg   = lane >> 4;
  const long plane = (long)blockIdx.x * HW;

  // Stage K row-major (coalesced 16B copies).
  for (int u = tid; u < 1152; u += 384) {
    int j = u / 12, c8 = u % 12;
    *(int4*)&sK[j * APITCH + c8 * 8] = *(const int4*)&k[plane + j * 96 + c8 * 8];
  }
  // Stage V transposed. j-major mapping: fixed c8 per wave-chunk, consecutive j
  // -> ds_write_b16 spreads across all 32 banks (2-way, free).
  for (int u = tid; u < 1152; u += 384) {
    int j = u % 96, c8 = u / 96;
    ushort tmp[8];
    *(int4*)tmp = *(const int4*)&v[plane + j * 96 + c8 * 8];
#pragma unroll
    for (int e = 0; e < 8; ++e)
      sVt[(c8 * 8 + e) * APITCH + j] = tmp[e];
  }
  __syncthreads();

  const int i0 = wv * 16;

  // Q fragments (B-operand): lane l15 = query col i, k = w chunk.
  bf16x8_t qf[3];
#pragma unroll
  for (int ks = 0; ks < 3; ++ks)
    qf[ks] = *(const bf16x8_t*)&q[plane + (i0 + l15) * 96 + ks * 32 + lg * 8];

  // S^T = K Q^T : 6 j-tiles x 3 k-steps.
  f32x4_t s[6];
#pragma unroll
  for (int jt = 0; jt < 6; ++jt) s[jt] = (f32x4_t){0.f, 0.f, 0.f, 0.f};
#pragma unroll
  for (int jt = 0; jt < 6; ++jt)
#pragma unroll
    for (int ks = 0; ks < 3; ++ks) {
      bf16x8_t kf = *(const bf16x8_t*)&sK[(jt * 16 + l15) * APITCH + ks * 32 + lg * 8];
      s[jt] = __builtin_amdgcn_mfma_f32_16x16x32_bf16(kf, qf[ks], s[jt], 0, 0, 0);
    }

  // Softmax over j for query i = i0 + l15 (24 values/lane + lanes l15+16lg).
  const float sc = 0.10206207261596575f;  // 1/sqrt(96)
  float m = -3.0e38f;
#pragma unroll
  for (int jt = 0; jt < 6; ++jt)
#pragma unroll
    for (int r = 0; r < 4; ++r) m = fmaxf(m, s[jt][r]);
  m = fmaxf(m, __shfl_xor(m, 16));
  m = fmaxf(m, __shfl_xor(m, 32));

  float p[6][4];
  float sum = 0.f;
#pragma unroll
  for (int jt = 0; jt < 6; ++jt)
#pragma unroll
    for (int r = 0; r < 4; ++r) {
      float e = __expf((s[jt][r] - m) * sc);
      p[jt][r] = e;
      sum += e;
    }
  sum += __shfl_xor(sum, 16);
  sum += __shfl_xor(sum, 32);
  const float inv = 1.f / sum;

  // P -> per-wave LDS as bf16, row i_local = l15, col j.
  ushort* myP = &sP[wv * 16 * APITCH];
#pragma unroll
  for (int jt = 0; jt < 6; ++jt) {
    *(uint*)&myP[l15 * APITCH + jt * 16 + lg * 4] =
        pk2_bf16(p[jt][0] * inv, p[jt][1] * inv);
    *(uint*)&myP[l15 * APITCH + jt * 16 + lg * 4 + 2] =
        pk2_bf16(p[jt][2] * inv, p[jt][3] * inv);
  }
  // Per-wave write->read: compiler inserts lgkmcnt; no barrier needed.

  // O = P V : A = P (row i, k j), B = V^T rows [w][j] (col w, k j).
  bf16x8_t pf[3];
#pragma unroll
  for (int ks = 0; ks < 3; ++ks)
    pf[ks] = *(const bf16x8_t*)&myP[l15 * APITCH + ks * 32 + lg * 8];

  f32x4_t o[6];
#pragma unroll
  for (int wt = 0; wt < 6; ++wt) o[wt] = (f32x4_t){0.f, 0.f, 0.f, 0.f};
#pragma unroll
  for (int wt = 0; wt < 6; ++wt)
#pragma unroll
    for (int ks = 0; ks < 3; ++ks) {
      bf16x8_t vf = *(const bf16x8_t*)&sVt[(wt * 16 + l15) * APITCH + ks * 32 + lg * 8];
      o[wt] = __builtin_amdgcn_mfma_f32_16x16x32_bf16(pf[ks], vf, o[wt], 0, 0, 0);
    }

  // O tile: row (lg*4+r) = i_local, col l15 = w_local.
#pragma unroll
  for (int wt = 0; wt < 6; ++wt)
#pragma unroll
    for (int r = 0; r < 4; ++r) {
      int i = i0 + lg * 4 + r;
      outf[plane + i * 96 + wt * 16 + l15] =
          __bfloat16_as_ushort(__float2bfloat16(o[wt][r]));
    }
}

// ---------------------------------------------------------------------------
extern "C" void kernel_launch(void* const* d_in, const int* in_sizes, int n_in,
                              void* d_out, int out_size, void* d_ws, size_t ws_size,
                              hipStream_t stream) {
  (void)in_sizes; (void)n_in; (void)out_size; (void)ws_size;

  const float* feats = (const float*)d_in[0];
  const float* graph = (const float*)d_in[1];
  const float* wq    = (const float*)d_in[2];
  const float* bq    = (const float*)d_in[3];
  const float* wk    = (const float*)d_in[4];
  const float* bk    = (const float*)d_in[5];
  const float* wv    = (const float*)d_in[6];
  const float* bv    = (const float*)d_in[7];
  const float* wo    = (const float*)d_in[8];
  const float* bo    = (const float*)d_in[9];
  float* out = (float*)d_out;

  char* ws = (char*)d_ws;
  const long planeB = PLANE_ELEMS * 2;                  // bf16 plane set: 37.7 MB
  ushort* qb   = (ushort*)ws;                           // q, then fused output
  ushort* kb   = (ushort*)(ws + planeB);
  ushort* vb   = (ushort*)(ws + 2 * planeB);
  ushort* nhwc = (ushort*)(ws + 3 * planeB);
  ushort* wtq  = (ushort*)(ws + 4 * planeB);
  ushort* wtk  = wtq + 9 * 256 * 256;
  ushort* wtv  = wtk + 9 * 256 * 256;
  ushort* wto  = wtv + 9 * 256 * 256;

  dim3 tgrid(HW / 32, CH / 32, BATCH);   // (288, 8, 8)
  dim3 wgrid(2304);
  dim3 cgrid(2, 48, BATCH);
  dim3 agrid(BATCH * CH);

  w_oihw_to_tap_bf16<<<wgrid, 256, 0, stream>>>(wq, wtq);
  w_oihw_to_tap_bf16<<<wgrid, 256, 0, stream>>>(wk, wtk);
  w_oihw_to_tap_bf16<<<wgrid, 256, 0, stream>>>(wv, wtv);
  w_oihw_to_tap_bf16<<<wgrid, 256, 0, stream>>>(wo, wto);

  nchw_f32_to_nhwc_bf16<<<tgrid, 256, 0, stream>>>(feats, nhwc);
  conv3x3_mfma<ushort><<<cgrid, 256, 0, stream>>>(nhwc, wtk, bk, kb);
  conv3x3_mfma<ushort><<<cgrid, 256, 0, stream>>>(nhwc, wtv, bv, vb);

  nchw_f32_to_nhwc_bf16<<<tgrid, 256, 0, stream>>>(graph, nhwc);
  conv3x3_mfma<ushort><<<cgrid, 256, 0, stream>>>(nhwc, wtq, bq, qb);

  attn_mfma<<<agrid, 384, 0, stream>>>(qb, kb, vb, qb);

  nchw_bf16_to_nhwc_bf16<<<tgrid, 256, 0, stream>>>(qb, nhwc);
  conv3x3_mfma<float><<<cgrid, 256, 0, stream>>>(nhwc, wto, bo, out);
}

// Round 4
// 666.095 us; speedup vs baseline: 20.9365x; 1.0618x over previous
//
#include <hip/hip_runtime.h>
#include <hip/hip_bf16.h>

// Problem constants
constexpr int BATCH = 8;
constexpr int CH    = 256;
constexpr int H     = 96;
constexpr int W     = 96;
constexpr int HW    = H * W;                         // 9216
constexpr long PLANE_ELEMS = (long)BATCH * CH * HW;  // 18,874,368

typedef short  bf16x8_t __attribute__((ext_vector_type(8)));
typedef float  f32x4_t  __attribute__((ext_vector_type(4)));

__device__ inline uint pk2_bf16(float a, float b) {
  ushort lo = __bfloat16_as_ushort(__float2bfloat16(a));
  ushort hi = __bfloat16_as_ushort(__float2bfloat16(b));
  return (uint)lo | ((uint)hi << 16);
}

// ---------------------------------------------------------------------------
// NCHW fp32 -> NHWC bf16 (tiled transpose). grid (HW/32, C/32, B), 256 thr.
// ---------------------------------------------------------------------------
__global__ __launch_bounds__(256) void nchw_f32_to_nhwc_bf16(
    const float* __restrict__ in, ushort* __restrict__ out)
{
  __shared__ float t[32][33];
  const int tid = threadIdx.x;
  const int p0 = blockIdx.x * 32;
  const int c0 = blockIdx.y * 32;
  const int b  = blockIdx.z;
  const int tp = tid & 31, tc8 = tid >> 5;
#pragma unroll
  for (int i = 0; i < 4; ++i) {
    int c = tc8 + i * 8;
    t[c][tp] = in[((long)(b * 256 + c0 + c)) * HW + p0 + tp];
  }
  __syncthreads();
  const int wc = tid & 31, wp8 = tid >> 5;
#pragma unroll
  for (int i = 0; i < 4; ++i) {
    int p = wp8 + i * 8;
    out[((long)b * HW + p0 + p) * 256 + c0 + wc] =
        __bfloat16_as_ushort(__float2bfloat16(t[wc][p]));
  }
}

// ---------------------------------------------------------------------------
// NCHW bf16 -> NHWC bf16 (for the fused attention output feeding conv O).
// ---------------------------------------------------------------------------
__global__ __launch_bounds__(256) void nchw_bf16_to_nhwc_bf16(
    const ushort* __restrict__ in, ushort* __restrict__ out)
{
  __shared__ ushort t[32][34];
  const int tid = threadIdx.x;
  const int p0 = blockIdx.x * 32;
  const int c0 = blockIdx.y * 32;
  const int b  = blockIdx.z;
  const int tp = tid & 31, tc8 = tid >> 5;
#pragma unroll
  for (int i = 0; i < 4; ++i) {
    int c = tc8 + i * 8;
    t[c][tp] = in[((long)(b * 256 + c0 + c)) * HW + p0 + tp];
  }
  __syncthreads();
  const int wc = tid & 31, wp8 = tid >> 5;
#pragma unroll
  for (int i = 0; i < 4; ++i) {
    int p = wp8 + i * 8;
    out[((long)b * HW + p0 + p) * 256 + c0 + wc] = t[wc][p];
  }
}

// ---------------------------------------------------------------------------
// Weights [Co,Ci,3,3] fp32 -> [tap][Co][Ci] bf16.  grid 2304 x 256.
// ---------------------------------------------------------------------------
__global__ __launch_bounds__(256) void w_oihw_to_tap_bf16(
    const float* __restrict__ w, ushort* __restrict__ wt)
{
  int idx = blockIdx.x * 256 + threadIdx.x;
  int ci  = idx & 255;
  int co  = (idx >> 8) & 255;
  int tap = idx >> 16;
  wt[idx] = __bfloat16_as_ushort(__float2bfloat16(w[(co * 256 + ci) * 9 + tap]));
}

// ---------------------------------------------------------------------------
// Conv 3x3 SAME via bf16 MFMA implicit GEMM (tap-decomposed), templated output.
// Block tile 128 co x 192 px (2 rows), wave 64co x 96px, mfma_f32_16x16x32_bf16.
// Round 4: single-buffered LDS (31.4 KB), no manual fragment reg-dbuf
// (compiler pipelines), __launch_bounds__(256,3) -> 3 blocks/CU (12 waves),
// XCD-bijective block swizzle (each XCD owns exactly one batch image -> input
// is L2-resident per XCD, ~1x HBM fetch).
// grid: 768 linear blocks = 2 co-halves x 48 y-tiles x 8 b.
// ---------------------------------------------------------------------------
__device__ inline void store_conv(float* out, long idx, float v) { out[idx] = v; }
__device__ inline void store_conv(ushort* out, long idx, float v) {
  out[idx] = __bfloat16_as_ushort(__float2bfloat16(v));
}

template <typename OutT>
__global__ __launch_bounds__(256, 3) void conv3x3_mfma(
    const ushort* __restrict__ in_nhwc,   // [B][96][96][256] bf16 bits
    const ushort* __restrict__ wt,        // [9][256][256] bf16 bits
    const float* __restrict__ bias,       // [256]
    OutT* __restrict__ out)               // [B][256][96][96]
{
  const int tid  = threadIdx.x;
  const int lane = tid & 63;
  const int wv   = tid >> 6;
  const int wm   = wv & 1;
  const int wn   = wv >> 1;
  const int l15  = lane & 15;
  const int lg   = lane >> 4;

  // Bijective XCD swizzle: 768 = 8 XCDs x 96 consecutive work items.
  // work = ((b*48 + yb)*2 + cox)  ->  XCD k handles exactly batch image k.
  const int lin = blockIdx.x;
  const int swz = (lin & 7) * 96 + (lin >> 3);
  const int cox = swz & 1;
  const int yb  = (swz >> 1) % 48;
  const int b   = (swz >> 1) / 48;
  const int co0 = cox * 128;
  const int y0  = yb * 2;

  __shared__ ushort sIn[4 * 98 * 40];   // single buffer, 31,360 B

  f32x4_t acc[4][6];
#pragma unroll
  for (int m = 0; m < 4; ++m)
#pragma unroll
    for (int n = 0; n < 6; ++n)
      acc[m][n] = (f32x4_t){0.f, 0.f, 0.f, 0.f};

  // 1568 16B units = 4 rr x 98 xx x 4 ci-groups
  auto stage_load = [&](int chunk, int4* regs) {
    const int ci0 = chunk * 32;
#pragma unroll
    for (int it = 0; it < 7; ++it) {
      int u = tid + it * 256;
      int4 v = make_int4(0, 0, 0, 0);
      if (u < 1568) {
        int g  = u & 3;
        int q  = u >> 2;
        int xx = q % 98;
        int rr = q / 98;
        int y = y0 - 1 + rr, x = xx - 1;
        if (y >= 0 && y < H && x >= 0 && x < W) {
          v = *(const int4*)&in_nhwc[((b * 96 + y) * 96 + x) * 256 + ci0 + g * 8];
        }
      }
      regs[it] = v;
    }
  };
  auto stage_write = [&](const int4* regs) {
#pragma unroll
    for (int it = 0; it < 7; ++it) {
      int u = tid + it * 256;
      if (u < 1568) {
        int g  = u & 3;
        int q  = u >> 2;
        int xx = q % 98;
        int rr = q / 98;
        *(int4*)((char*)&sIn[0] + (rr * 98 + xx) * 80 + g * 16) = regs[it];
      }
    }
  };
  auto lds_b = [&](int rr, int xx) -> bf16x8_t {
    return *(const bf16x8_t*)((const char*)&sIn[0] + (rr * 98 + xx) * 80 + lg * 16);
  };
  auto gld_a = [&](int tap, int m, int ci0) -> bf16x8_t {
    int co = co0 + wm * 64 + m * 16 + l15;
    return *(const bf16x8_t*)&wt[((tap * 256 + co) << 8) + ci0 + lg * 8];
  };

  int4 pre[7];
  stage_load(0, pre);

  for (int c = 0; c < 8; ++c) {
    __syncthreads();                 // all waves done reading previous chunk
    stage_write(pre);
    if (c < 7) stage_load(c + 1, pre);   // issue next chunk's global loads early
    __syncthreads();                 // staged tile visible

    const int ci0 = c * 32;
#pragma unroll
    for (int tap = 0; tap < 9; ++tap) {
      const int dy = tap / 3, dx = tap % 3;
      bf16x8_t a[4], bf[6];
#pragma unroll
      for (int m = 0; m < 4; ++m) a[m] = gld_a(tap, m, ci0);
#pragma unroll
      for (int n = 0; n < 6; ++n) bf[n] = lds_b(wn + dy, n * 16 + l15 + dx);
#pragma unroll
      for (int m = 0; m < 4; ++m)
#pragma unroll
        for (int n = 0; n < 6; ++n)
          acc[m][n] = __builtin_amdgcn_mfma_f32_16x16x32_bf16(
              a[m], bf[n], acc[m][n], 0, 0, 0);
    }
  }

  // Epilogue: bias + store. C/D layout: col = lane&15 -> pixel, row -> co.
  const int y = y0 + wn;
#pragma unroll
  for (int m = 0; m < 4; ++m) {
    const int cobase = co0 + wm * 64 + m * 16 + lg * 4;
#pragma unroll
    for (int r = 0; r < 4; ++r) {
      const int co = cobase + r;
      const float bv = bias[co];
#pragma unroll
      for (int n = 0; n < 6; ++n) {
        store_conv(out, ((long)(b * 256 + co) * 96 + y) * 96 + n * 16 + l15,
                   acc[m][n][r] + bv);
      }
    }
  }
}

// ---------------------------------------------------------------------------
// MFMA row attention. One block (384 thr = 6 waves) per (b,c) plane.
// ---------------------------------------------------------------------------
constexpr int APITCH = 104;   // LDS row pitch in bf16 elems (208 B)

__global__ __launch_bounds__(384, 3) void attn_mfma(
    const ushort* __restrict__ q,
    const ushort* __restrict__ k,
    const ushort* __restrict__ v,
    ushort* __restrict__ outf)
{
  __shared__ ushort sK [96 * APITCH];       // [j][w]
  __shared__ ushort sVt[96 * APITCH];       // [w][j]  (V transposed)
  __shared__ ushort sP [6 * 16 * APITCH];   // per-wave [i_local][j]

  const int tid  = threadIdx.x;
  const int lane = tid & 63;
  const int wv   = tid >> 6;
  const int l15  = lane & 15;
  const int lg   = lane >> 4;
  const long plane = (long)blockIdx.x * HW;

  for (int u = tid; u < 1152; u += 384) {
    int j = u / 12, c8 = u % 12;
    *(int4*)&sK[j * APITCH + c8 * 8] = *(const int4*)&k[plane + j * 96 + c8 * 8];
  }
  for (int u = tid; u < 1152; u += 384) {
    int j = u % 96, c8 = u / 96;
    ushort tmp[8];
    *(int4*)tmp = *(const int4*)&v[plane + j * 96 + c8 * 8];
#pragma unroll
    for (int e = 0; e < 8; ++e)
      sVt[(c8 * 8 + e) * APITCH + j] = tmp[e];
  }
  __syncthreads();

  const int i0 = wv * 16;

  bf16x8_t qf[3];
#pragma unroll
  for (int ks = 0; ks < 3; ++ks)
    qf[ks] = *(const bf16x8_t*)&q[plane + (i0 + l15) * 96 + ks * 32 + lg * 8];

  f32x4_t s[6];
#pragma unroll
  for (int jt = 0; jt < 6; ++jt) s[jt] = (f32x4_t){0.f, 0.f, 0.f, 0.f};
#pragma unroll
  for (int jt = 0; jt < 6; ++jt)
#pragma unroll
    for (int ks = 0; ks < 3; ++ks) {
      bf16x8_t kf = *(const bf16x8_t*)&sK[(jt * 16 + l15) * APITCH + ks * 32 + lg * 8];
      s[jt] = __builtin_amdgcn_mfma_f32_16x16x32_bf16(kf, qf[ks], s[jt], 0, 0, 0);
    }

  const float sc = 0.10206207261596575f;  // 1/sqrt(96)
  float m = -3.0e38f;
#pragma unroll
  for (int jt = 0; jt < 6; ++jt)
#pragma unroll
    for (int r = 0; r < 4; ++r) m = fmaxf(m, s[jt][r]);
  m = fmaxf(m, __shfl_xor(m, 16));
  m = fmaxf(m, __shfl_xor(m, 32));

  float p[6][4];
  float sum = 0.f;
#pragma unroll
  for (int jt = 0; jt < 6; ++jt)
#pragma unroll
    for (int r = 0; r < 4; ++r) {
      float e = __expf((s[jt][r] - m) * sc);
      p[jt][r] = e;
      sum += e;
    }
  sum += __shfl_xor(sum, 16);
  sum += __shfl_xor(sum, 32);
  const float inv = 1.f / sum;

  ushort* myP = &sP[wv * 16 * APITCH];
#pragma unroll
  for (int jt = 0; jt < 6; ++jt) {
    *(uint*)&myP[l15 * APITCH + jt * 16 + lg * 4] =
        pk2_bf16(p[jt][0] * inv, p[jt][1] * inv);
    *(uint*)&myP[l15 * APITCH + jt * 16 + lg * 4 + 2] =
        pk2_bf16(p[jt][2] * inv, p[jt][3] * inv);
  }

  bf16x8_t pf[3];
#pragma unroll
  for (int ks = 0; ks < 3; ++ks)
    pf[ks] = *(const bf16x8_t*)&myP[l15 * APITCH + ks * 32 + lg * 8];

  f32x4_t o[6];
#pragma unroll
  for (int wt = 0; wt < 6; ++wt) o[wt] = (f32x4_t){0.f, 0.f, 0.f, 0.f};
#pragma unroll
  for (int wt = 0; wt < 6; ++wt)
#pragma unroll
    for (int ks = 0; ks < 3; ++ks) {
      bf16x8_t vf = *(const bf16x8_t*)&sVt[(wt * 16 + l15) * APITCH + ks * 32 + lg * 8];
      o[wt] = __builtin_amdgcn_mfma_f32_16x16x32_bf16(pf[ks], vf, o[wt], 0, 0, 0);
    }

#pragma unroll
  for (int wt = 0; wt < 6; ++wt)
#pragma unroll
    for (int r = 0; r < 4; ++r) {
      int i = i0 + lg * 4 + r;
      outf[plane + i * 96 + wt * 16 + l15] =
          __bfloat16_as_ushort(__float2bfloat16(o[wt][r]));
    }
}

// ---------------------------------------------------------------------------
extern "C" void kernel_launch(void* const* d_in, const int* in_sizes, int n_in,
                              void* d_out, int out_size, void* d_ws, size_t ws_size,
                              hipStream_t stream) {
  (void)in_sizes; (void)n_in; (void)out_size; (void)ws_size;

  const float* feats = (const float*)d_in[0];
  const float* graph = (const float*)d_in[1];
  const float* wq    = (const float*)d_in[2];
  const float* bq    = (const float*)d_in[3];
  const float* wk    = (const float*)d_in[4];
  const float* bk    = (const float*)d_in[5];
  const float* wv    = (const float*)d_in[6];
  const float* bv    = (const float*)d_in[7];
  const float* wo    = (const float*)d_in[8];
  const float* bo    = (const float*)d_in[9];
  float* out = (float*)d_out;

  char* ws = (char*)d_ws;
  const long planeB = PLANE_ELEMS * 2;                  // bf16 plane set
  ushort* qb   = (ushort*)ws;                           // q, then fused output
  ushort* kb   = (ushort*)(ws + planeB);
  ushort* vb   = (ushort*)(ws + 2 * planeB);
  ushort* nhwc = (ushort*)(ws + 3 * planeB);
  ushort* wtq  = (ushort*)(ws + 4 * planeB);
  ushort* wtk  = wtq + 9 * 256 * 256;
  ushort* wtv  = wtk + 9 * 256 * 256;
  ushort* wto  = wtv + 9 * 256 * 256;

  dim3 tgrid(HW / 32, CH / 32, BATCH);   // (288, 8, 8)
  dim3 wgrid(2304);
  dim3 agrid(BATCH * CH);

  w_oihw_to_tap_bf16<<<wgrid, 256, 0, stream>>>(wq, wtq);
  w_oihw_to_tap_bf16<<<wgrid, 256, 0, stream>>>(wk, wtk);
  w_oihw_to_tap_bf16<<<wgrid, 256, 0, stream>>>(wv, wtv);
  w_oihw_to_tap_bf16<<<wgrid, 256, 0, stream>>>(wo, wto);

  nchw_f32_to_nhwc_bf16<<<tgrid, 256, 0, stream>>>(feats, nhwc);
  conv3x3_mfma<ushort><<<768, 256, 0, stream>>>(nhwc, wtk, bk, kb);
  conv3x3_mfma<ushort><<<768, 256, 0, stream>>>(nhwc, wtv, bv, vb);

  nchw_f32_to_nhwc_bf16<<<tgrid, 256, 0, stream>>>(graph, nhwc);
  conv3x3_mfma<ushort><<<768, 256, 0, stream>>>(nhwc, wtq, bq, qb);

  attn_mfma<<<agrid, 384, 0, stream>>>(qb, kb, vb, qb);

  nchw_bf16_to_nhwc_bf16<<<tgrid, 256, 0, stream>>>(qb, nhwc);
  conv3x3_mfma<float><<<768, 256, 0, stream>>>(nhwc, wto, bo, out);
}

// Round 5
// 501.016 us; speedup vs baseline: 27.8348x; 1.3295x over previous
//
#include <hip/hip_runtime.h>
#include <hip/hip_bf16.h>

// Problem constants
constexpr int BATCH = 8;
constexpr int CH    = 256;
constexpr int H     = 96;
constexpr int W     = 96;
constexpr int HW    = H * W;                         // 9216
constexpr long PLANE_ELEMS = (long)BATCH * CH * HW;  // 18,874,368
constexpr int PAD   = 98;                            // padded spatial dim

typedef short  bf16x8_t __attribute__((ext_vector_type(8)));
typedef float  f32x4_t  __attribute__((ext_vector_type(4)));

__device__ inline uint pk2_bf16(float a, float b) {
  ushort lo = __bfloat16_as_ushort(__float2bfloat16(a));
  ushort hi = __bfloat16_as_ushort(__float2bfloat16(b));
  return (uint)lo | ((uint)hi << 16);
}

#define WAITVM(N) asm volatile("s_waitcnt vmcnt(" #N ")" ::: "memory")

__device__ __forceinline__ void gl_lds16(const ushort* g, ushort* l) {
  __builtin_amdgcn_global_load_lds(
      (const __attribute__((address_space(1))) void*)g,
      (__attribute__((address_space(3))) void*)l, 16, 0, 0);
}

// ---------------------------------------------------------------------------
// NCHW fp32 -> padded NHWC bf16 ([B][98][98][256], borders pre-zeroed by
// memset). grid (HW/32, C/32, B), 256 thr.
// ---------------------------------------------------------------------------
__global__ __launch_bounds__(256) void nchw_f32_to_nhwc_bf16(
    const float* __restrict__ in, ushort* __restrict__ out)
{
  __shared__ float t[32][33];
  const int tid = threadIdx.x;
  const int p0 = blockIdx.x * 32;
  const int c0 = blockIdx.y * 32;
  const int b  = blockIdx.z;
  const int tp = tid & 31, tc8 = tid >> 5;
#pragma unroll
  for (int i = 0; i < 4; ++i) {
    int c = tc8 + i * 8;
    t[c][tp] = in[((long)(b * 256 + c0 + c)) * HW + p0 + tp];
  }
  __syncthreads();
  const int wc = tid & 31, wp8 = tid >> 5;
#pragma unroll
  for (int i = 0; i < 4; ++i) {
    int p = p0 + wp8 + i * 8;
    int y = p / 96, x = p % 96;
    out[(((long)b * PAD + y + 1) * PAD + x + 1) * 256 + c0 + wc] =
        __bfloat16_as_ushort(__float2bfloat16(t[wc][wp8 + i * 8]));
  }
}

// ---------------------------------------------------------------------------
// NCHW bf16 -> padded NHWC bf16 (fused attention output feeding conv O).
// ---------------------------------------------------------------------------
__global__ __launch_bounds__(256) void nchw_bf16_to_nhwc_bf16(
    const ushort* __restrict__ in, ushort* __restrict__ out)
{
  __shared__ ushort t[32][34];
  const int tid = threadIdx.x;
  const int p0 = blockIdx.x * 32;
  const int c0 = blockIdx.y * 32;
  const int b  = blockIdx.z;
  const int tp = tid & 31, tc8 = tid >> 5;
#pragma unroll
  for (int i = 0; i < 4; ++i) {
    int c = tc8 + i * 8;
    t[c][tp] = in[((long)(b * 256 + c0 + c)) * HW + p0 + tp];
  }
  __syncthreads();
  const int wc = tid & 31, wp8 = tid >> 5;
#pragma unroll
  for (int i = 0; i < 4; ++i) {
    int p = p0 + wp8 + i * 8;
    int y = p / 96, x = p % 96;
    out[(((long)b * PAD + y + 1) * PAD + x + 1) * 256 + c0 + wc] = t[wc][wp8 + i * 8];
  }
}

// ---------------------------------------------------------------------------
// Weights [Co,Ci,3,3] fp32 -> [tap][Co][Ci] bf16.  grid 2304 x 256.
// ---------------------------------------------------------------------------
__global__ __launch_bounds__(256) void w_oihw_to_tap_bf16(
    const float* __restrict__ w, ushort* __restrict__ wt)
{
  int idx = blockIdx.x * 256 + threadIdx.x;
  int ci  = idx & 255;
  int co  = (idx >> 8) & 255;
  int tap = idx >> 16;
  wt[idx] = __bfloat16_as_ushort(__float2bfloat16(w[(co * 256 + ci) * 9 + tap]));
}

// ---------------------------------------------------------------------------
// Conv 3x3 SAME via bf16 MFMA, 72-phase pipelined (9 taps x 8 ci-chunks).
// Per phase: vmcnt(N) -> s_barrier -> issue A(t+2) gload_lds -> ds_read A,B
// -> 24 MFMA (setprio-wrapped). A: 3-slot LDS rotation, 2-phase lead.
// Input: padded-global gload_lds, double-buffered, issued 7 phases ahead.
// XOR-swizzled layouts on both sides (2-way bank max). LDS 80KB -> 2 blk/CU.
// grid: 768 linear = 2 co-halves x 48 y-tiles x 8 b, XCD-bijective swizzle.
// ---------------------------------------------------------------------------
__device__ inline void store_conv(float* out, long idx, float v) { out[idx] = v; }
__device__ inline void store_conv(ushort* out, long idx, float v) {
  out[idx] = __bfloat16_as_ushort(__float2bfloat16(v));
}

template <typename OutT>
__global__ __launch_bounds__(256, 2) void conv3x3_mfma(
    const ushort* __restrict__ pin,       // [B][98][98][256] padded NHWC bf16
    const ushort* __restrict__ wt,        // [9][256][256] bf16 bits
    const float* __restrict__ bias,       // [256]
    OutT* __restrict__ out)               // [B][256][96][96]
{
  const int tid  = threadIdx.x;
  const int lane = tid & 63;
  const int wv   = tid >> 6;
  const int wm   = wv & 1;        // co half (64 co)
  const int wn   = wv >> 1;       // row within 2-row tile
  const int l15  = lane & 15;
  const int lg   = lane >> 4;

  // Bijective XCD swizzle: 768 = 8 XCDs x 96; XCD k owns batch image k.
  const int lin = blockIdx.x;
  const int swz = (lin & 7) * 96 + (lin >> 3);
  const int cox = swz & 1;
  const int yb  = (swz >> 1) % 48;
  const int b   = (swz >> 1) / 48;
  const int co0 = cox * 128;
  const int y0  = yb * 2;

  __shared__ ushort sIn[2][1792 * 8];   // 2 x 28,672 B  (4 rr x 112 xx x 32 ci)
  __shared__ ushort sA [3][512 * 8];    // 3 x  8,192 B  (128 co x 32 ci)

  f32x4_t acc[4][6];
#pragma unroll
  for (int m = 0; m < 4; ++m)
#pragma unroll
    for (int n = 0; n < 6; ++n)
      acc[m][n] = (f32x4_t){0.f, 0.f, 0.f, 0.f};

  // A-read swizzle offset: thread-constant (see derivation: SWZ(co)=(co+(co>>2))&3
  // reduces to a function of l15 only within a fragment).
  const int aoff = (lg ^ ((l15 + (l15 >> 2)) & 3)) << 4;

  // Stage 8KB A-tile (tap, ci-chunk) into slot via gload_lds, 2 instr/thread.
  auto issueA = [&](int cc, int tap, int slot) {
    if (cc >= 8) return;
    const int ci0 = cc * 32;
#pragma unroll
    for (int r = 0; r < 2; ++r) {
      int L  = r * 256 + wv * 64 + lane;
      int co = L >> 2;
      int u  = (L & 3) ^ ((co + (co >> 2)) & 3);    // pre-swizzled source
      const ushort* src = wt + ((tap * 256 + co0 + co) << 8) + ci0 + u * 8;
      ushort* dst = (ushort*)((char*)&sA[slot][0] + (r * 256 + wv * 64) * 16);
      gl_lds16(src, dst);
    }
  };

  // Stage 28KB input tile (ci-chunk cc) into buf cc&1, 7 instr/thread.
  auto issueIN = [&](int cc) {
    if (cc >= 8) return;
    const int ci0 = cc * 32;
#pragma unroll
    for (int r = 0; r < 7; ++r) {
      int L  = r * 256 + wv * 64 + lane;
      int q  = L >> 2;
      int xx = q % 112, rr = q / 112;               // xx 98..111 = junk (unused)
      int u  = (L & 3) ^ ((xx + (xx >> 2)) & 3);    // pre-swizzled source
      const ushort* src = pin + (((long)(b * PAD + y0 + rr)) * PAD + xx) * 256 + ci0 + u * 8;
      ushort* dst = (ushort*)((char*)&sIn[cc & 1][0] + (r * 256 + wv * 64) * 16);
      gl_lds16(src, dst);
    }
  };

  auto dotap = [&](int DY, int DX, int bi, int slot) {
    bf16x8_t a[4], bb[6];
    const char* Ab = (const char*)&sA[slot][0];
#pragma unroll
    for (int m = 0; m < 4; ++m)
      a[m] = *(const bf16x8_t*)(Ab + ((wm * 64 + m * 16 + l15) << 6) + aoff);
    const char* Bb = (const char*)&sIn[bi][0];
    const int s    = l15 + DX;
    const int boff = (lg ^ ((s + (s >> 2)) & 3)) << 4;   // swizzled read
    const int rr   = wn + DY;
#pragma unroll
    for (int n = 0; n < 6; ++n)
      bb[n] = *(const bf16x8_t*)(Bb + ((rr * 112 + n * 16 + s) << 6) + boff);
    __builtin_amdgcn_s_setprio(1);
#pragma unroll
    for (int m = 0; m < 4; ++m)
#pragma unroll
      for (int n = 0; n < 6; ++n)
        acc[m][n] = __builtin_amdgcn_mfma_f32_16x16x32_bf16(
            a[m], bb[n], acc[m][n], 0, 0, 0);
    __builtin_amdgcn_s_setprio(0);
  };

  // Per-phase: wait OWN A(t) loads (vmcnt) BEFORE barrier => after barrier the
  // full cooperative A-tile is visible (all waves waited). Issue A(t+2) AFTER
  // the barrier (its slot's last readers finished before this barrier).
#define CPHASE(TAP, VMN, EXTRA)                                            \
  WAITVM(VMN);                                                             \
  __builtin_amdgcn_s_barrier();                                            \
  __builtin_amdgcn_sched_barrier(0);                                       \
  issueA(c + (TAP + 2) / 9, (TAP + 2) % 9, (TAP + 2) % 3);                 \
  EXTRA                                                                    \
  dotap(TAP / 3, TAP % 3, c & 1, TAP % 3);

  // Prologue: A(0), A(1), IN(0) in flight; drain; barrier.
  issueA(0, 0, 0);
  issueA(0, 1, 1);
  issueIN(0);
  WAITVM(0);
  __builtin_amdgcn_s_barrier();
  __builtin_amdgcn_sched_barrier(0);

  // vmcnt ledger (per wave, FIFO): steady state = {A(t),A(t+1)} = 4 ->
  // wait A(t) = vmcnt(2). Chunk phases t=3,4 carry the 7 IN loads issued at
  // t=2 -> vmcnt(9); t=5's vmcnt(2) implicitly drains IN (3 phases old).
#pragma unroll 1
  for (int c = 0; c < 7; ++c) {
    CPHASE(0, 2, )
    CPHASE(1, 2, )
    CPHASE(2, 2, issueIN(c + 1);)
    CPHASE(3, 9, )
    CPHASE(4, 9, )
    CPHASE(5, 2, )
    CPHASE(6, 2, )
    CPHASE(7, 2, )
    CPHASE(8, 2, )
  }
  {
    const int c = 7;   // last chunk: no IN prefetch; pipeline drains
    CPHASE(0, 2, )
    CPHASE(1, 2, )
    CPHASE(2, 2, )
    CPHASE(3, 2, )
    CPHASE(4, 2, )
    CPHASE(5, 2, )
    CPHASE(6, 2, )
    CPHASE(7, 2, )
    CPHASE(8, 0, )
  }
#undef CPHASE

  // Epilogue: bias + store. C/D layout: col = lane&15 -> pixel, row -> co.
  const int y = y0 + wn;
#pragma unroll
  for (int m = 0; m < 4; ++m) {
    const int cobase = co0 + wm * 64 + m * 16 + lg * 4;
#pragma unroll
    for (int r = 0; r < 4; ++r) {
      const int co = cobase + r;
      const float bv = bias[co];
#pragma unroll
      for (int n = 0; n < 6; ++n) {
        store_conv(out, ((long)(b * 256 + co) * 96 + y) * 96 + n * 16 + l15,
                   acc[m][n][r] + bv);
      }
    }
  }
}

// ---------------------------------------------------------------------------
// MFMA row attention. One block (384 thr = 6 waves) per (b,c) plane.
// (unchanged from round 3)
// ---------------------------------------------------------------------------
constexpr int APITCH = 104;

__global__ __launch_bounds__(384, 3) void attn_mfma(
    const ushort* __restrict__ q,
    const ushort* __restrict__ k,
    const ushort* __restrict__ v,
    ushort* __restrict__ outf)
{
  __shared__ ushort sK [96 * APITCH];
  __shared__ ushort sVt[96 * APITCH];
  __shared__ ushort sP [6 * 16 * APITCH];

  const int tid  = threadIdx.x;
  const int lane = tid & 63;
  const int wv   = tid >> 6;
  const int l15  = lane & 15;
  const int lg   = lane >> 4;
  const long plane = (long)blockIdx.x * HW;

  for (int u = tid; u < 1152; u += 384) {
    int j = u / 12, c8 = u % 12;
    *(int4*)&sK[j * APITCH + c8 * 8] = *(const int4*)&k[plane + j * 96 + c8 * 8];
  }
  for (int u = tid; u < 1152; u += 384) {
    int j = u % 96, c8 = u / 96;
    ushort tmp[8];
    *(int4*)tmp = *(const int4*)&v[plane + j * 96 + c8 * 8];
#pragma unroll
    for (int e = 0; e < 8; ++e)
      sVt[(c8 * 8 + e) * APITCH + j] = tmp[e];
  }
  __syncthreads();

  const int i0 = wv * 16;

  bf16x8_t qf[3];
#pragma unroll
  for (int ks = 0; ks < 3; ++ks)
    qf[ks] = *(const bf16x8_t*)&q[plane + (i0 + l15) * 96 + ks * 32 + lg * 8];

  f32x4_t s[6];
#pragma unroll
  for (int jt = 0; jt < 6; ++jt) s[jt] = (f32x4_t){0.f, 0.f, 0.f, 0.f};
#pragma unroll
  for (int jt = 0; jt < 6; ++jt)
#pragma unroll
    for (int ks = 0; ks < 3; ++ks) {
      bf16x8_t kf = *(const bf16x8_t*)&sK[(jt * 16 + l15) * APITCH + ks * 32 + lg * 8];
      s[jt] = __builtin_amdgcn_mfma_f32_16x16x32_bf16(kf, qf[ks], s[jt], 0, 0, 0);
    }

  const float sc = 0.10206207261596575f;  // 1/sqrt(96)
  float m = -3.0e38f;
#pragma unroll
  for (int jt = 0; jt < 6; ++jt)
#pragma unroll
    for (int r = 0; r < 4; ++r) m = fmaxf(m, s[jt][r]);
  m = fmaxf(m, __shfl_xor(m, 16));
  m = fmaxf(m, __shfl_xor(m, 32));

  float p[6][4];
  float sum = 0.f;
#pragma unroll
  for (int jt = 0; jt < 6; ++jt)
#pragma unroll
    for (int r = 0; r < 4; ++r) {
      float e = __expf((s[jt][r] - m) * sc);
      p[jt][r] = e;
      sum += e;
    }
  sum += __shfl_xor(sum, 16);
  sum += __shfl_xor(sum, 32);
  const float inv = 1.f / sum;

  ushort* myP = &sP[wv * 16 * APITCH];
#pragma unroll
  for (int jt = 0; jt < 6; ++jt) {
    *(uint*)&myP[l15 * APITCH + jt * 16 + lg * 4] =
        pk2_bf16(p[jt][0] * inv, p[jt][1] * inv);
    *(uint*)&myP[l15 * APITCH + jt * 16 + lg * 4 + 2] =
        pk2_bf16(p[jt][2] * inv, p[jt][3] * inv);
  }

  bf16x8_t pf[3];
#pragma unroll
  for (int ks = 0; ks < 3; ++ks)
    pf[ks] = *(const bf16x8_t*)&myP[l15 * APITCH + ks * 32 + lg * 8];

  f32x4_t o[6];
#pragma unroll
  for (int wt = 0; wt < 6; ++wt) o[wt] = (f32x4_t){0.f, 0.f, 0.f, 0.f};
#pragma unroll
  for (int wt = 0; wt < 6; ++wt)
#pragma unroll
    for (int ks = 0; ks < 3; ++ks) {
      bf16x8_t vf = *(const bf16x8_t*)&sVt[(wt * 16 + l15) * APITCH + ks * 32 + lg * 8];
      o[wt] = __builtin_amdgcn_mfma_f32_16x16x32_bf16(pf[ks], vf, o[wt], 0, 0, 0);
    }

#pragma unroll
  for (int wt = 0; wt < 6; ++wt)
#pragma unroll
    for (int r = 0; r < 4; ++r) {
      int i = i0 + lg * 4 + r;
      outf[plane + i * 96 + wt * 16 + l15] =
          __bfloat16_as_ushort(__float2bfloat16(o[wt][r]));
    }
}

// ---------------------------------------------------------------------------
extern "C" void kernel_launch(void* const* d_in, const int* in_sizes, int n_in,
                              void* d_out, int out_size, void* d_ws, size_t ws_size,
                              hipStream_t stream) {
  (void)in_sizes; (void)n_in; (void)out_size; (void)ws_size;

  const float* feats = (const float*)d_in[0];
  const float* graph = (const float*)d_in[1];
  const float* wq    = (const float*)d_in[2];
  const float* bq    = (const float*)d_in[3];
  const float* wk    = (const float*)d_in[4];
  const float* bk    = (const float*)d_in[5];
  const float* wv    = (const float*)d_in[6];
  const float* bv    = (const float*)d_in[7];
  const float* wo    = (const float*)d_in[8];
  const float* bo    = (const float*)d_in[9];
  float* out = (float*)d_out;

  char* ws = (char*)d_ws;
  const long planeB = PLANE_ELEMS * 2;                 // 37.75 MB per bf16 set
  const long pinElems = (long)BATCH * PAD * PAD * 256; // padded NHWC
  ushort* qb  = (ushort*)ws;                           // q, then fused output
  ushort* kb  = (ushort*)(ws + planeB);
  ushort* vb  = (ushort*)(ws + 2 * planeB);
  ushort* pin = (ushort*)(ws + 3 * planeB);            // 39.3 MB padded NHWC
  ushort* wtq = (ushort*)(ws + 3 * planeB + pinElems * 2);
  ushort* wtk = wtq + 9 * 256 * 256;
  ushort* wtv = wtk + 9 * 256 * 256;
  ushort* wto = wtv + 9 * 256 * 256;

  dim3 tgrid(HW / 32, CH / 32, BATCH);   // (288, 8, 8)
  dim3 wgrid(2304);
  dim3 agrid(BATCH * CH);

  // Zero the padded buffer once per launch (borders stay 0; interiors are
  // fully rewritten by each transpose).
  hipMemsetAsync(pin, 0, pinElems * 2, stream);

  w_oihw_to_tap_bf16<<<wgrid, 256, 0, stream>>>(wq, wtq);
  w_oihw_to_tap_bf16<<<wgrid, 256, 0, stream>>>(wk, wtk);
  w_oihw_to_tap_bf16<<<wgrid, 256, 0, stream>>>(wv, wtv);
  w_oihw_to_tap_bf16<<<wgrid, 256, 0, stream>>>(wo, wto);

  nchw_f32_to_nhwc_bf16<<<tgrid, 256, 0, stream>>>(feats, pin);
  conv3x3_mfma<ushort><<<768, 256, 0, stream>>>(pin, wtk, bk, kb);
  conv3x3_mfma<ushort><<<768, 256, 0, stream>>>(pin, wtv, bv, vb);

  nchw_f32_to_nhwc_bf16<<<tgrid, 256, 0, stream>>>(graph, pin);
  conv3x3_mfma<ushort><<<768, 256, 0, stream>>>(pin, wtq, bq, qb);

  attn_mfma<<<agrid, 384, 0, stream>>>(qb, kb, vb, qb);

  nchw_bf16_to_nhwc_bf16<<<tgrid, 256, 0, stream>>>(qb, pin);
  conv3x3_mfma<float><<<768, 256, 0, stream>>>(pin, wto, bo, out);
}